// Round 8
// baseline (338.976 us; speedup 1.0000x reference)
//
#include <hip/hip_runtime.h>
#include <cstdint>
#include <cstddef>

// Problem constants (fixed shapes from setup_inputs)
#define IN_DIM  1024
#define OUT_DIM 1024
#define NB      7
#define KTOT    8192   // interleaved: k = i*8 + {x, basis0..basis6}
#define BROWS   8192   // batch

typedef unsigned short u16;
typedef __attribute__((ext_vector_type(8))) short bf16x8;
typedef __attribute__((ext_vector_type(8))) unsigned short u16x8;
typedef __attribute__((ext_vector_type(4))) float f32x4;

__device__ __forceinline__ u16 f2bf(float f) {
    union { float f; unsigned int u; } v; v.f = f;
    unsigned int r = (v.u + 0x7fffu + ((v.u >> 16) & 1u)) >> 16;  // RTN-even
    return (u16)r;
}

__device__ __forceinline__ void gl_lds16(const u16* g, u16* l) {
    __builtin_amdgcn_global_load_lds(
        (const __attribute__((address_space(1))) void*)g,
        (__attribute__((address_space(3))) void*)l,
        16, 0, 0);
}

// ---------------------------------------------------------------------------
// prep_wsw: Bt[o][i*8+0] = bf16(W[o][i]); Bt[o][i*8+1+k] = bf16(sw[i][o][k]).
__global__ __launch_bounds__(256) void prep_wsw(const float* __restrict__ sw,
                                                const float* __restrict__ W,
                                                u16* __restrict__ Bt) {
    __shared__ u16 S[8 * 256 * 8];               // [il][ol][slot], 32 KB
    const int i0 = blockIdx.x * 8;
    const int o0 = blockIdx.y * 256;
    const int t  = threadIdx.x;
    #pragma unroll
    for (int il = 0; il < 8; ++il) {
        const float* src = sw + ((size_t)(i0 + il) * OUT_DIM + o0) * NB;
        for (int c = t; c < 256 * NB; c += 256) {
            int ol = c / 7, k = c - ol * 7;
            S[(il * 256 + ol) * 8 + 1 + k] = f2bf(src[c]);
        }
    }
    for (int c = t; c < 2048; c += 256) {
        int ol = c >> 3, il = c & 7;
        S[(il * 256 + ol) * 8] = f2bf(W[(size_t)(o0 + ol) * IN_DIM + i0 + il]);
    }
    __syncthreads();
    for (int c = t; c < 2048; c += 256) {
        int ol = c >> 3, il = c & 7;   // consecutive t -> contiguous 16B writes
        *(u16x8*)&Bt[(size_t)(o0 + ol) * KTOT + (size_t)(i0 + il) * 8] =
            *(const u16x8*)&S[(il * 256 + ol) * 8];
    }
}

// ---------------------------------------------------------------------------
// prep_a: A[b][i*8+0] = bf16(x[b][i]); A[b][i*8+1+k] = bf16(basis_k(tanh(x))).
// Fast tanh via __expf identity (err ~2^-21, invisible under bf16 rounding).
__global__ __launch_bounds__(256) void prep_a(const float* __restrict__ x,
                                              u16* __restrict__ A, int row0) {
    int gid = blockIdx.x * 256 + threadIdx.x;
    int b = gid >> 10;
    int i = gid & 1023;
    float xv = x[(size_t)(row0 + b) * IN_DIM + i];

    float e = __expf(2.f * xv);
    float t = 1.f - 2.f / (e + 1.f);             // tanh(xv)
    t = fminf(fmaxf(t, -1.f), 1.f);

    const float kn[11] = {-1.f, -0.8f, -0.6f, -0.4f, -0.2f, 0.f,
                           0.2f, 0.4f, 0.6f, 0.8f, 1.f};
    float bb[8];
    #pragma unroll
    for (int j = 0; j < 7; ++j)
        bb[j] = (t >= kn[j] && t < kn[j + 1]) ? 1.f : 0.f;
    bb[7] = 0.f;

    const float rcp[4] = {0.f, 5.f, 2.5f, 5.f / 3.f};  // 1/(0.2*d)
    #pragma unroll
    for (int d = 1; d <= 3; ++d) {
        #pragma unroll
        for (int j = 0; j < 7; ++j) {
            float left  = (t - kn[j]) * rcp[d];
            float right = (kn[j + d + 1] - t) * rcp[d];
            bb[j] = left * bb[j] + right * bb[j + 1];
        }
    }
    u16x8 outv;
    outv[0] = f2bf(xv);
    #pragma unroll
    for (int k = 0; k < NB; ++k) outv[1 + k] = f2bf(bb[k]);
    *(u16x8*)&A[(size_t)b * KTOT + (size_t)i * 8] = outv;
}

// ---------------------------------------------------------------------------
// gemm_bt v8 = v7 with tile 128x64 (BK=128): LDS 48 KB/block -> 3 blocks/CU,
// 12 waves/CU (was 2 blocks/8 waves, both grid- and LDS-capped). More resident
// blocks de-synchronize the barrier-drain windows (m114 co-scheduling), which
// is the remaining stall. Wave tile 64x32 = acc[4][2]. Same XOR swizzle
// (phys_chunk = q ^ (row & 15), writer qsw = (t&15)^(t>>4), reader pq ^ lm)
// -> measured 0 conflicts. XCD swizzle: 16 n-tiles of one m-tile share
// blockIdx%8 (same XCD) for A-tile L2 sharing.
__global__ __launch_bounds__(256) void gemm_bt(const u16* __restrict__ A,
                                               const u16* __restrict__ Bt,
                                               const float* __restrict__ bias,
                                               float* __restrict__ C) {
    __shared__ __align__(16) u16 As[128 * 128];   // 32 KB
    __shared__ __align__(16) u16 Bs[64 * 128];    // 16 KB
    const int t = threadIdx.x;
    const int L = t & 63;
    const int w = t >> 6;
    const int wm = w & 1, wn = w >> 1;            // wm: m-half, wn: n-half(32)

    const int Lid = blockIdx.x;
    const int idx = Lid >> 3;
    const int n_t = idx & 15;
    const int m_t = (Lid & 7) + 8 * (idx >> 4);
    const int m0 = m_t * 128;
    const int n0 = n_t * 64;

    f32x4 acc[4][2] = {};

    // staging: A 8 slots, B 4 slots per thread; slot s = g*256 + t
    const int trow = t >> 4;                   // 0..15
    const int qsw  = (t & 15) ^ trow;          // logical chunk to fetch
    const u16* gA[8]; const u16* gB[4];
    u16* lA[8]; u16* lB[4];
    #pragma unroll
    for (int g = 0; g < 8; ++g) {
        gA[g] = A + (size_t)(m0 + 16 * g + trow) * KTOT + qsw * 8;
        lA[g] = &As[(256 * g + t) * 8];
    }
    #pragma unroll
    for (int g = 0; g < 4; ++g) {
        gB[g] = Bt + (size_t)(n0 + 16 * g + trow) * KTOT + qsw * 8;
        lB[g] = &Bs[(256 * g + t) * 8];
    }

    const int lm  = L & 15;
    const int qd  = L >> 4;                    // quad 0..3

    for (int ko = 0; ko < KTOT; ko += 128) {
        __syncthreads();
        #pragma unroll
        for (int g = 0; g < 8; ++g) gl_lds16(gA[g] + ko, lA[g]);
        #pragma unroll
        for (int g = 0; g < 4; ++g) gl_lds16(gB[g] + ko, lB[g]);
        __syncthreads();

        #pragma unroll
        for (int ks = 0; ks < 4; ++ks) {
            const int pq = ((ks * 4 + qd) ^ lm) * 8;
            bf16x8 af[4], bfr[2];
            #pragma unroll
            for (int mi = 0; mi < 4; ++mi)
                af[mi] = *(const bf16x8*)&As[(wm * 64 + mi * 16 + lm) * 128 + pq];
            #pragma unroll
            for (int ni = 0; ni < 2; ++ni)
                bfr[ni] = *(const bf16x8*)&Bs[(wn * 32 + ni * 16 + lm) * 128 + pq];
            #pragma unroll
            for (int mi = 0; mi < 4; ++mi)
                #pragma unroll
                for (int ni = 0; ni < 2; ++ni)
                    acc[mi][ni] = __builtin_amdgcn_mfma_f32_16x16x32_bf16(
                        af[mi], bfr[ni], acc[mi][ni], 0, 0, 0);
        }
    }

    // epilogue: C/D layout col=lane&15, row=(lane>>4)*4+reg (m89-verified)
    const int r0 = qd * 4;
    #pragma unroll
    for (int ni = 0; ni < 2; ++ni) {
        int col = n0 + wn * 32 + ni * 16 + lm;
        float bv = bias[col];
        #pragma unroll
        for (int mi = 0; mi < 4; ++mi) {
            int rb = m0 + wm * 64 + mi * 16 + r0;
            f32x4 v = acc[mi][ni];
            #pragma unroll
            for (int rr = 0; rr < 4; ++rr)
                C[(size_t)(rb + rr) * OUT_DIM + col] = v[rr] + bv;
        }
    }
}

// ---------------------------------------------------------------------------
extern "C" void kernel_launch(void* const* d_in, const int* in_sizes, int n_in,
                              void* d_out, int out_size, void* d_ws, size_t ws_size,
                              hipStream_t stream) {
    (void)in_sizes; (void)n_in; (void)out_size;
    const float* x    = (const float*)d_in[0];
    const float* sw   = (const float*)d_in[1];
    const float* W    = (const float*)d_in[2];
    const float* bias = (const float*)d_in[3];
    float* out = (float*)d_out;

    const size_t btBytes = (size_t)OUT_DIM * KTOT * 2;     // 16 MB
    u16* Bt = (u16*)d_ws;
    u16* A  = (u16*)((char*)d_ws + btBytes);

    prep_wsw<<<dim3(IN_DIM / 8, OUT_DIM / 256), 256, 0, stream>>>(sw, W, Bt);

    int nchunks = 1;
    if (ws_size < btBytes + (size_t)BROWS * KTOT * 2)       nchunks = 2;
    if (ws_size < btBytes + (size_t)(BROWS / 2) * KTOT * 2) nchunks = 4;
    if (ws_size < btBytes + (size_t)(BROWS / 4) * KTOT * 2) nchunks = 8;
    const int rows = BROWS / nchunks;

    for (int c = 0; c < nchunks; ++c) {
        int row0 = c * rows;
        prep_a<<<rows * 4, 256, 0, stream>>>(x, A, row0);
        gemm_bt<<<dim3((rows / 128) * 16), 256, 0, stream>>>(
            A, Bt, bias, out + (size_t)row0 * OUT_DIM);
    }
}